// Round 2
// baseline (922.677 us; speedup 1.0000x reference)
//
#include <hip/hip_runtime.h>

// Problem constants (B=4, S=2048, H=1024, E=8, F=4096, K=2)
#define T_TOKENS 8192
#define H_DIM 1024
#define E_EXP 8
#define F_DIM 4096
#define CAP 8192      // slot capacity per expert in tok/wt arrays
#define MT256 16      // 256-row m-tiles per expert (covers 4096 rows, 48 sigma)

typedef __attribute__((ext_vector_type(8))) short short8;
typedef __attribute__((ext_vector_type(8))) unsigned short ushort8;
typedef __attribute__((ext_vector_type(4))) float f32x4;

__device__ __forceinline__ unsigned short f2bf(float f) {
    unsigned int u = __float_as_uint(f);
    u += 0x7fffu + ((u >> 16) & 1u);   // round-to-nearest-even
    return (unsigned short)(u >> 16);
}

__device__ __forceinline__ float gelu_tanh(float x) {
    // jax.nn.gelu default (approximate=True)
    float z = 0.7978845608028654f * (x + 0.044715f * x * x * x);
    float t = 1.0f - 2.0f / (__expf(2.0f * z) + 1.0f);   // tanh(z)
    return 0.5f * x * (1.0f + t);
}

// async 16B global->LDS DMA (lane i of the wave lands at wave-uniform base + i*16)
__device__ __forceinline__ void gld16(const void* g, void* l) {
    __builtin_amdgcn_global_load_lds(
        (const __attribute__((address_space(1))) unsigned int*)g,
        (__attribute__((address_space(3))) unsigned int*)l,
        16, 0, 0);
}

// ---------------- router: top-2 + softmax; block-aggregated slot assignment --------
__global__ void router_kernel(const float* __restrict__ logits,
                              int* __restrict__ cnt,
                              int* __restrict__ tok,
                              float* __restrict__ wt) {
    __shared__ int hcnt[E_EXP];
    __shared__ int hbase[E_EXP];
    int tid = threadIdx.x;
    if (tid < E_EXP) hcnt[tid] = 0;
    __syncthreads();
    int t = blockIdx.x * 256 + tid;
    float l[E_EXP];
#pragma unroll
    for (int i = 0; i < E_EXP; i++) l[i] = logits[t * E_EXP + i];
    int i0 = 0; float s0 = l[0];
#pragma unroll
    for (int i = 1; i < E_EXP; i++) if (l[i] > s0) { s0 = l[i]; i0 = i; }
    int i1 = (i0 == 0) ? 1 : 0; float s1 = l[i1];
#pragma unroll
    for (int i = 0; i < E_EXP; i++) if (i != i0 && l[i] > s1) { s1 = l[i]; i1 = i; }
    float p0 = 1.0f / (1.0f + __expf(s1 - s0));
    float p1 = 1.0f - p0;
    int lo0 = atomicAdd(&hcnt[i0], 1);   // LDS atomic (fast, 8 addrs)
    int lo1 = atomicAdd(&hcnt[i1], 1);
    __syncthreads();
    if (tid < E_EXP) hbase[tid] = atomicAdd(&cnt[tid], hcnt[tid]);  // 8 global atomics/block
    __syncthreads();
    int sl0 = hbase[i0] + lo0;
    tok[i0 * CAP + sl0] = t; wt[i0 * CAP + sl0] = p0;
    int sl1 = hbase[i1] + lo1;
    tok[i1 * CAP + sl1] = t; wt[i1 * CAP + sl1] = p1;
}

__global__ void base_kernel(const int* __restrict__ cnt, int* __restrict__ base) {
    if (threadIdx.x == 0) {
        int b = 0;
        for (int e = 0; e < E_EXP; e++) { base[e] = b; b += cnt[e]; }
    }
}

// ---------------- x fp32 -> bf16 ----------------
__global__ void cvtx_kernel(const float* __restrict__ x, unsigned short* __restrict__ xg) {
    int i = blockIdx.x * 256 + threadIdx.x;   // over T*H/4
    float4 v = ((const float4*)x)[i];
    ushort4 o;
    o.x = f2bf(v.x); o.y = f2bf(v.y); o.z = f2bf(v.z); o.w = f2bf(v.w);
    ((ushort4*)xg)[i] = o;
}

// ---------------- transpose + convert: in [M,N] fp32 -> out [N,M] bf16 (per expert z)
__global__ void tcvt_kernel(const float* __restrict__ in, unsigned short* __restrict__ out,
                            int M, int N) {
    __shared__ float t[64][65];
    size_t eoff = (size_t)blockIdx.z * M * N;
    in += eoff; out += eoff;
    int r0 = blockIdx.x * 64, c0 = blockIdx.y * 64;
    int tid = threadIdx.x;
    int srow = tid >> 4;            // 0..15
    int scol = (tid & 15) * 4;
#pragma unroll
    for (int p = 0; p < 4; p++) {
        int row = p * 16 + srow;
        float4 v = *(const float4*)&in[(size_t)(r0 + row) * N + c0 + scol];
        t[row][scol + 0] = v.x; t[row][scol + 1] = v.y;
        t[row][scol + 2] = v.z; t[row][scol + 3] = v.w;
    }
    __syncthreads();
    int orow = tid >> 3;            // 0..31
    int ocb = (tid & 7) * 8;        // out col base (in-row index)
#pragma unroll
    for (int p = 0; p < 2; p++) {
        int r = p * 32 + orow;      // local out row (= in col)
        ushort8 o;
#pragma unroll
        for (int i = 0; i < 8; i++) o[i] = f2bf(t[ocb + i][r]);
        *(ushort8*)&out[(size_t)(c0 + r) * M + r0 + ocb] = o;
    }
}

// ---------------- grouped GEMM: 256x256 tile, BK=32, ring-4 LDS, depth-3 prefetch ----
// C[m,n] = sum_k A[m,k] * B[n,k]   (B pre-transposed, k contiguous)
// GATHER=1: A row m of expert e is xg[tok[e*CAP+m]]     (GEMM1)
// GATHER=0: A row m of expert e is G[base[e]+m]         (GEMM2)
// EPI=0: gelu -> bf16 G[(base+m)*N + n]
// EPI=1: atomicAdd(out[tok*N + n], wt * val)            (split-K safe)
//
// Pipeline (fixes round-1 stall): 4-deep LDS ring of 32-KiB K-tiles (A+B, BK=32).
//   Iteration t stages tile t+3 (4 x global_load_lds/thread) then waits a COUNTED
//   vmcnt(12) (= tiles t+1..t+3 stay in flight) -> tile t is landed, prefetch
//   distance ~3 compute iterations covers L2-miss/HBM latency even at 1 block/CU.
//   Main loop never drains vmcnt to 0 (T4). BK=32 row stride = 64 B (16 banks):
//   even/odd rows alternate bank halves -> ds_read_b128 frags are conflict-free
//   with the natural linear layout (no swizzle needed; DMA dest stays linear).
//   WAR safety: tile t+4 overwrites buf (t&3) only after iteration t's end-barrier,
//   and each wave lgkm-drains its ds_reads before its MFMAs (hence before barrier).
//   setprio(1) around the MFMA cluster (T5). XCD chunking (T1) with (ntl x mtl)
//   block-tiles per XCD so concurrently-streamed A slices + B panels fit 4 MiB L2.
template <int GATHER, int EPI, int NT, int KSPLIT, int NTL, int MTL>
__global__ __launch_bounds__(512, 2)
void gemm256_kernel(const unsigned short* __restrict__ Asrc,
                    const unsigned short* __restrict__ Bt,
                    int K, int N,
                    const int* __restrict__ cnt, const int* __restrict__ base,
                    const int* __restrict__ tok, const float* __restrict__ wt,
                    unsigned short* __restrict__ Gout, float* __restrict__ out) {
    const int nwg = E_EXP * MT256 * NT * KSPLIT;   // grid size, multiple of 8
    int bid = blockIdx.x;
    int u = (bid & 7) * (nwg >> 3) + (bid >> 3);   // XCD-chunked bijective remap
    // digits fastest->slowest: ntl, mtl, ntb, mtb, ks, e  (all powers of 2)
    const int ntl = u % NTL; u /= NTL;
    const int mtl = u % MTL; u /= MTL;
    const int ntb = u % (NT / NTL); u /= (NT / NTL);
    const int mtb = u % (MT256 / MTL); u /= (MT256 / MTL);
    const int ks = u % KSPLIT; u /= KSPLIT;
    const int e = u;
    const int nt = ntb * NTL + ntl;
    const int mt = mtb * MTL + mtl;

    const int cnt_e = cnt[e];
    const int m0 = mt * 256;
    if (m0 >= cnt_e) return;                       // uniform exit, before any barrier
    const int base_e = base[e];
    const int n0 = nt * 256;
    const int Kp = K / KSPLIT;
    const int kbegin = ks * Kp;
    const int KT = Kp >> 5;                        // K-tiles of 32 (>= 3 for both GEMMs)

    const int tid = threadIdx.x;
    const int lane = tid & 63;
    const int wave = tid >> 6;
    const int l16 = lane & 15, quad = lane >> 4;
    const int wmg = wave >> 2;                     // 2 m-groups of 128 rows
    const int wng = wave & 3;                      // 4 n-groups of 64 cols

    // ring of 4 K-tile buffers: [buf][row(256)][k(32)] ; 64 KiB + 64 KiB = 128 KiB
    __shared__ unsigned short As[4][256][32];
    __shared__ unsigned short Bs[4][256][32];

    // ---- staging source pointers (4 gld16 per thread per K-tile) ----
    const int rsel = tid >> 2;                     // 0..127
    const int ksel = (tid & 3) * 8;                // k-chunk (elements)
    const unsigned short* arow[2];
    const unsigned short* brow[2];
#pragma unroll
    for (int p = 0; p < 2; p++) {
        int gr = m0 + p * 128 + rsel;
        if (gr > cnt_e - 1) gr = cnt_e - 1;        // tail clamp (epilogue guards)
        const unsigned short* ab;
        if (GATHER) ab = Asrc + (size_t)tok[e * CAP + gr] * K;
        else        ab = Asrc + (size_t)(base_e + gr) * K;
        arow[p] = ab + kbegin + ksel;
        brow[p] = Bt + (size_t)e * N * K + (size_t)(n0 + p * 128 + rsel) * K + kbegin + ksel;
    }
    unsigned short* alds = &As[0][0][0];
    unsigned short* blds = &Bs[0][0][0];
    const int dst = tid * 8;                       // shorts; linear DMA dest
    const int TSH = 256 * 32;                      // shorts per tile buffer

    auto stage = [&](int b, int koff) {
        gld16(arow[0] + koff, alds + b * TSH + dst);
        gld16(arow[1] + koff, alds + b * TSH + 4096 + dst);
        gld16(brow[0] + koff, blds + b * TSH + dst);
        gld16(brow[1] + koff, blds + b * TSH + 4096 + dst);
    };

    f32x4 acc[8][4];
#pragma unroll
    for (int i = 0; i < 8; i++)
#pragma unroll
        for (int j = 0; j < 4; j++) acc[i][j] = (f32x4){0.f, 0.f, 0.f, 0.f};

    const int kq = quad * 8;                       // lane's k-chunk within the 32-k tile

    // prologue: fill 3 ring slots (12 loads in flight)
    stage(0, 0); stage(1, 32); stage(2, 64);

    for (int t = 0; t < KT; ++t) {
        const int cur = t & 3;
        if (t + 3 < KT) {
            stage((t + 3) & 3, (t + 3) * 32);
            // keep tiles t+1..t+3 (12 loads) in flight; tile t is landed
            asm volatile("s_waitcnt vmcnt(12)\n\ts_barrier" ::: "memory");
        } else if (t + 3 == KT) {
            asm volatile("s_waitcnt vmcnt(8)\n\ts_barrier" ::: "memory");
        } else if (t + 2 == KT) {
            asm volatile("s_waitcnt vmcnt(4)\n\ts_barrier" ::: "memory");
        } else {
            asm volatile("s_waitcnt vmcnt(0)\n\ts_barrier" ::: "memory");
        }

        short8 bfr[4];
#pragma unroll
        for (int j = 0; j < 4; j++)
            bfr[j] = *(const short8*)&Bs[cur][wng * 64 + j * 16 + l16][kq];
        short8 afr[8];
#pragma unroll
        for (int i = 0; i < 8; i++)
            afr[i] = *(const short8*)&As[cur][wmg * 128 + i * 16 + l16][kq];

        __builtin_amdgcn_s_setprio(1);
#pragma unroll
        for (int i = 0; i < 8; i++)
#pragma unroll
            for (int j = 0; j < 4; j++)
                acc[i][j] = __builtin_amdgcn_mfma_f32_16x16x32_bf16(afr[i], bfr[j], acc[i][j], 0, 0, 0);
        __builtin_amdgcn_s_setprio(0);

        // all this wave's ds_reads completed (lgkm drained before MFMAs) -> buffer
        // (t&3) may be overwritten by the stage issued after this barrier
        asm volatile("s_barrier" ::: "memory");
    }

    // epilogue: D row = quad*4 + reg, D col = l16 (within each 16x16 tile)
    if (EPI == 0) {
#pragma unroll
        for (int i = 0; i < 8; i++) {
            int lm = wmg * 128 + i * 16 + quad * 4;
#pragma unroll
            for (int r = 0; r < 4; r++) {
                int gr = m0 + lm + r;
                if (gr < cnt_e) {
                    size_t rowoff = (size_t)(base_e + gr) * N;
#pragma unroll
                    for (int j = 0; j < 4; j++) {
                        int ncol = n0 + wng * 64 + j * 16 + l16;
                        Gout[rowoff + ncol] = f2bf(gelu_tanh(acc[i][j][r]));
                    }
                }
            }
        }
    } else {
#pragma unroll
        for (int i = 0; i < 8; i++) {
            int lm = wmg * 128 + i * 16 + quad * 4;
#pragma unroll
            for (int r = 0; r < 4; r++) {
                int gr = m0 + lm + r;
                if (gr < cnt_e) {
                    int tk = tok[e * CAP + gr];
                    float w = wt[e * CAP + gr];
                    float* orow = out + (size_t)tk * N;
#pragma unroll
                    for (int j = 0; j < 4; j++) {
                        int ncol = n0 + wng * 64 + j * 16 + l16;
                        atomicAdd(&orow[ncol], w * acc[i][j][r]);
                    }
                }
            }
        }
    }
}

extern "C" void kernel_launch(void* const* d_in, const int* in_sizes, int n_in,
                              void* d_out, int out_size, void* d_ws, size_t ws_size,
                              hipStream_t stream) {
    const float* x      = (const float*)d_in[0];
    const float* logits = (const float*)d_in[1];
    const float* w1     = (const float*)d_in[2];
    const float* w2     = (const float*)d_in[3];
    float* out = (float*)d_out;
    char* ws = (char*)d_ws;

    // workspace layout
    const size_t OFF_CNT  = 0;
    const size_t OFF_BASE = 64;
    const size_t OFF_TOK  = 1024;
    const size_t OFF_WT   = OFF_TOK + (size_t)E_EXP * CAP * 4;
    const size_t OFF_XG   = 1u << 20;
    const size_t OFF_W1T  = OFF_XG + (size_t)T_TOKENS * H_DIM * 2;
    const size_t OFF_W2T  = OFF_W1T + (size_t)E_EXP * H_DIM * F_DIM * 2;
    const size_t OFF_G    = OFF_W2T + (size_t)E_EXP * H_DIM * F_DIM * 2;

    int* cnt  = (int*)(ws + OFF_CNT);
    int* base = (int*)(ws + OFF_BASE);
    int* tok  = (int*)(ws + OFF_TOK);
    float* wt = (float*)(ws + OFF_WT);
    unsigned short* xg  = (unsigned short*)(ws + OFF_XG);
    unsigned short* w1t = (unsigned short*)(ws + OFF_W1T);
    unsigned short* w2t = (unsigned short*)(ws + OFF_W2T);
    unsigned short* G   = (unsigned short*)(ws + OFF_G);

    hipMemsetAsync(d_out, 0, (size_t)out_size * sizeof(float), stream);
    hipMemsetAsync(cnt, 0, 64, stream);

    router_kernel<<<T_TOKENS / 256, 256, 0, stream>>>(logits, cnt, tok, wt);
    base_kernel<<<1, 64, 0, stream>>>(cnt, base);
    cvtx_kernel<<<(T_TOKENS * H_DIM / 4) / 256, 256, 0, stream>>>(x, xg);
    // w1 [E,H,F] -> w1t [E,F,H]
    tcvt_kernel<<<dim3(H_DIM / 64, F_DIM / 64, E_EXP), 256, 0, stream>>>(w1, w1t, H_DIM, F_DIM);
    // w2 [E,F,H] -> w2t [E,H,F]
    tcvt_kernel<<<dim3(F_DIM / 64, H_DIM / 64, E_EXP), 256, 0, stream>>>(w2, w2t, F_DIM, H_DIM);
    // GEMM1: 256x256 tiles, NT=16 (F=4096), no K-split, 4x4 L2 block. grid = 2048
    gemm256_kernel<1, 0, 16, 1, 4, 4><<<E_EXP * MT256 * 16 * 1, 512, 0, stream>>>(
        xg, w1t, H_DIM, F_DIM, cnt, base, tok, wt, G, nullptr);
    // GEMM2: 256x256 tiles, NT=4 (H=1024), split-K=2, 2x2 L2 block. grid = 1024
    gemm256_kernel<0, 1, 4, 2, 2, 2><<<E_EXP * MT256 * 4 * 2, 512, 0, stream>>>(
        G, w2t, F_DIM, H_DIM, cnt, base, tok, wt, nullptr, out);
    (void)in_sizes; (void)n_in; (void)ws_size;
}

// Round 3
// 742.008 us; speedup vs baseline: 1.2435x; 1.2435x over previous
//
#include <hip/hip_runtime.h>

// Problem constants (B=4, S=2048, H=1024, E=8, F=4096, K=2)
#define T_TOKENS 8192
#define H_DIM 1024
#define E_EXP 8
#define F_DIM 4096
#define CAP 8192      // slot capacity per expert in tok/wt arrays
#define MT_TILES 32   // m-tiles per expert in GEMM grid

typedef __attribute__((ext_vector_type(8))) short short8;
typedef __attribute__((ext_vector_type(8))) unsigned short ushort8;
typedef __attribute__((ext_vector_type(4))) float f32x4;

__device__ __forceinline__ unsigned short f2bf(float f) {
    unsigned int u = __float_as_uint(f);
    u += 0x7fffu + ((u >> 16) & 1u);   // round-to-nearest-even
    return (unsigned short)(u >> 16);
}

__device__ __forceinline__ float gelu_tanh(float x) {
    // jax.nn.gelu default (approximate=True)
    float z = 0.7978845608028654f * (x + 0.044715f * x * x * x);
    float t = 1.0f - 2.0f / (__expf(2.0f * z) + 1.0f);   // tanh(z)
    return 0.5f * x * (1.0f + t);
}

// async 16B global->LDS DMA (lane i of the wave lands at ldsbase + i*16)
__device__ __forceinline__ void gld16(const void* g, void* l) {
    __builtin_amdgcn_global_load_lds(
        (const __attribute__((address_space(1))) unsigned int*)g,
        (__attribute__((address_space(3))) unsigned int*)l,
        16, 0, 0);
}

// ---------------- router: top-2 + softmax; block-aggregated slot assignment --------
__global__ void router_kernel(const float* __restrict__ logits,
                              int* __restrict__ cnt,
                              int* __restrict__ tok,
                              float* __restrict__ wt) {
    __shared__ int hcnt[E_EXP];
    __shared__ int hbase[E_EXP];
    int tid = threadIdx.x;
    if (tid < E_EXP) hcnt[tid] = 0;
    __syncthreads();
    int t = blockIdx.x * 256 + tid;
    float l[E_EXP];
#pragma unroll
    for (int i = 0; i < E_EXP; i++) l[i] = logits[t * E_EXP + i];
    int i0 = 0; float s0 = l[0];
#pragma unroll
    for (int i = 1; i < E_EXP; i++) if (l[i] > s0) { s0 = l[i]; i0 = i; }
    int i1 = (i0 == 0) ? 1 : 0; float s1 = l[i1];
#pragma unroll
    for (int i = 0; i < E_EXP; i++) if (i != i0 && l[i] > s1) { s1 = l[i]; i1 = i; }
    float p0 = 1.0f / (1.0f + __expf(s1 - s0));
    float p1 = 1.0f - p0;
    int lo0 = atomicAdd(&hcnt[i0], 1);   // LDS atomic (fast, 8 addrs)
    int lo1 = atomicAdd(&hcnt[i1], 1);
    __syncthreads();
    if (tid < E_EXP) hbase[tid] = atomicAdd(&cnt[tid], hcnt[tid]);  // 8 global atomics/block
    __syncthreads();
    int sl0 = hbase[i0] + lo0;
    tok[i0 * CAP + sl0] = t; wt[i0 * CAP + sl0] = p0;
    int sl1 = hbase[i1] + lo1;
    tok[i1 * CAP + sl1] = t; wt[i1 * CAP + sl1] = p1;
}

__global__ void base_kernel(const int* __restrict__ cnt, int* __restrict__ base) {
    if (threadIdx.x == 0) {
        int b = 0;
        for (int e = 0; e < E_EXP; e++) { base[e] = b; b += cnt[e]; }
    }
}

// ---------------- x fp32 -> bf16 ----------------
__global__ void cvtx_kernel(const float* __restrict__ x, unsigned short* __restrict__ xg) {
    int i = blockIdx.x * 256 + threadIdx.x;   // over T*H/4
    float4 v = ((const float4*)x)[i];
    ushort4 o;
    o.x = f2bf(v.x); o.y = f2bf(v.y); o.z = f2bf(v.z); o.w = f2bf(v.w);
    ((ushort4*)xg)[i] = o;
}

// ---------------- transpose + convert: in [M,N] fp32 -> out [N,M] bf16 (per expert z)
__global__ void tcvt_kernel(const float* __restrict__ in, unsigned short* __restrict__ out,
                            int M, int N) {
    __shared__ float t[64][65];
    size_t eoff = (size_t)blockIdx.z * M * N;
    in += eoff; out += eoff;
    int r0 = blockIdx.x * 64, c0 = blockIdx.y * 64;
    int tid = threadIdx.x;
    int srow = tid >> 4;            // 0..15
    int scol = (tid & 15) * 4;
#pragma unroll
    for (int p = 0; p < 4; p++) {
        int row = p * 16 + srow;
        float4 v = *(const float4*)&in[(size_t)(r0 + row) * N + c0 + scol];
        t[row][scol + 0] = v.x; t[row][scol + 1] = v.y;
        t[row][scol + 2] = v.z; t[row][scol + 3] = v.w;
    }
    __syncthreads();
    int orow = tid >> 3;            // 0..31
    int ocb = (tid & 7) * 8;        // out col base (in-row index)
#pragma unroll
    for (int p = 0; p < 2; p++) {
        int r = p * 32 + orow;      // local out row (= in col)
        ushort8 o;
#pragma unroll
        for (int i = 0; i < 8; i++) o[i] = f2bf(t[ocb + i][r]);
        *(ushort8*)&out[(size_t)(c0 + r) * M + r0 + ocb] = o;
    }
}

// ---------------- grouped GEMM (m97 staging + XCD partition + BK=64) ----------------
// C[m,n] = sum_k A[m,k] * B[n,k]   (B pre-transposed, k contiguous)
// GATHER=1: A row m of expert e is xg[tok[e*CAP+m]]     (GEMM1)
// GATHER=0: A row m of expert e is G[base[e]+m]         (GEMM2)
// EPI=0: gelu -> bf16 G[(base+m)*N + n]
// EPI=1: atomicAdd(out[tok*N + n], wt * val)
// Partition: xcd = bid&7. MC m-groups (xcd & (MC-1)), xcd/MC owns NT8 n-tiles.
// m-tiles interleaved by parity across groups for load balance.
//
// T2 LDS swizzle (fixes measured 1.74e7 SQ_LDS_BANK_CONFLICT): the [128][32]-short
// tile has a 64 B row stride, so linear chunk placement puts 8 same-parity rows
// on one 4-bank group per ds_read_b128 (8-way conflict). We XOR the 16 B k-chunk
// index with ((row>>1)&3) -> 2 lanes/bank-group (free, m136). Rule #21: DMA dest
// stays linear; the SAME XOR is applied to the per-lane global source chunk and
// to the read address (involution, coalescing preserved within each 64 B span).
template <int GATHER, int EPI, int NT8, int MC>
__global__ __launch_bounds__(256, 4)
void gemm_kernel(const unsigned short* __restrict__ Asrc,
                 const unsigned short* __restrict__ Bt,
                 int K, int N,
                 const int* __restrict__ cnt, const int* __restrict__ base,
                 const int* __restrict__ tok, const float* __restrict__ wt,
                 unsigned short* __restrict__ Gout, float* __restrict__ out) {
    int bid = blockIdx.x;
    int xcd = bid & 7;
    int q = bid >> 3;
    int nl = q % NT8;                       // n fastest within XCD (B band L2-hot)
    int q2 = q / NT8;
    const int MTG = MT_TILES / MC;          // m-tiles per group
    int mt = q2 % MTG;
    const int e = q2 / MTG;
    const int g = xcd & (MC - 1);
    const int n_tile = (xcd / MC) * NT8 + nl;
    const int m_tile = mt * MC + g;         // parity-interleaved

    const int cnt_e = cnt[e];
    const int m0 = m_tile * 128;
    if (m0 >= cnt_e) return;
    const int base_e = base[e];
    const int n0 = n_tile * 128;
    const int tid = threadIdx.x;
    const int lane = tid & 63;
    const int wave = tid >> 6;
    const int quad = lane >> 4, l16 = lane & 15;
    const int wm = (wave & 1) * 64, wn = (wave >> 1) * 64;

    // BK=64 as two 32-k half tiles; each half keeps the wave-linear DMA layout
    __shared__ unsigned short As[2][128][32];
    __shared__ unsigned short Bs[2][128][32];

    const int srow = wave * 16 + (lane >> 2);   // row within 64-row group
    // swizzled k-chunk: linear LDS slot (row, lane&3) holds global chunk
    // (lane&3) ^ ((row>>1)&3); for this staging map (row>>1)&3 == (lane>>3)&3
    const int vsw = (lane >> 3) & 3;
    const int selem = ((lane & 3) ^ vsw) * 8;   // k elem within 32-k half (swizzled)
    const unsigned short* aptr[2];
    const unsigned short* bptr[2];
#pragma unroll
    for (int p = 0; p < 2; p++) {
        int gr = m0 + p * 64 + srow;
        if (gr > cnt_e - 1) gr = cnt_e - 1;     // tail clamp (epilogue guards)
        const unsigned short* arow;
        if (GATHER) arow = Asrc + (size_t)tok[e * CAP + gr] * K;
        else        arow = Asrc + (size_t)(base_e + gr) * K;
        aptr[p] = arow + selem;
        bptr[p] = Bt + (size_t)e * (size_t)N * K + (size_t)(n0 + p * 64 + srow) * K + selem;
    }
    unsigned short* alds0 = &As[0][wave * 16][0];
    unsigned short* alds1 = &As[0][64 + wave * 16][0];
    unsigned short* blds0 = &Bs[0][wave * 16][0];
    unsigned short* blds1 = &Bs[0][64 + wave * 16][0];
    const int HALF = 128 * 32;   // shorts per half tile

    f32x4 acc[4][4];
#pragma unroll
    for (int i = 0; i < 4; i++)
#pragma unroll
        for (int j = 0; j < 4; j++) acc[i][j] = (f32x4){0.f, 0.f, 0.f, 0.f};

    // read-side swizzle: fragment row = wm/wn + i*16 + l16 -> (row>>1)&3 == (l16>>1)&3
    const int kx = ((quad ^ ((l16 >> 1) & 3)) * 8);

    for (int k0 = 0; k0 < K; k0 += 64) {
#pragma unroll
        for (int sub = 0; sub < 2; sub++) {
            gld16(aptr[0] + k0 + sub * 32, alds0 + sub * HALF);
            gld16(aptr[1] + k0 + sub * 32, alds1 + sub * HALF);
            gld16(bptr[0] + k0 + sub * 32, blds0 + sub * HALF);
            gld16(bptr[1] + k0 + sub * 32, blds1 + sub * HALF);
        }
        __syncthreads();
#pragma unroll
        for (int sub = 0; sub < 2; sub++) {
            short8 af[4], bf[4];
#pragma unroll
            for (int i = 0; i < 4; i++)
                af[i] = *(const short8*)&As[sub][wm + i * 16 + l16][kx];
#pragma unroll
            for (int j = 0; j < 4; j++)
                bf[j] = *(const short8*)&Bs[sub][wn + j * 16 + l16][kx];
#pragma unroll
            for (int i = 0; i < 4; i++)
#pragma unroll
                for (int j = 0; j < 4; j++)
                    acc[i][j] = __builtin_amdgcn_mfma_f32_16x16x32_bf16(af[i], bf[j], acc[i][j], 0, 0, 0);
        }
        __syncthreads();
    }

    // epilogue: D row = quad*4 + reg, D col = l16 (within each 16x16 tile)
    if (EPI == 0) {
#pragma unroll
        for (int i = 0; i < 4; i++) {
            int lm = wm + i * 16 + quad * 4;
#pragma unroll
            for (int r = 0; r < 4; r++) {
                int gr = m0 + lm + r;
                if (gr < cnt_e) {
                    size_t rowoff = (size_t)(base_e + gr) * N;
#pragma unroll
                    for (int j = 0; j < 4; j++) {
                        int ncol = n0 + wn + j * 16 + l16;
                        Gout[rowoff + ncol] = f2bf(gelu_tanh(acc[i][j][r]));
                    }
                }
            }
        }
    } else {
#pragma unroll
        for (int i = 0; i < 4; i++) {
            int lm = wm + i * 16 + quad * 4;
#pragma unroll
            for (int r = 0; r < 4; r++) {
                int gr = m0 + lm + r;
                if (gr < cnt_e) {
                    int tk = tok[e * CAP + gr];
                    float w = wt[e * CAP + gr];
                    float* orow = out + (size_t)tk * N;
#pragma unroll
                    for (int j = 0; j < 4; j++) {
                        int ncol = n0 + wn + j * 16 + l16;
                        atomicAdd(&orow[ncol], w * acc[i][j][r]);
                    }
                }
            }
        }
    }
}

extern "C" void kernel_launch(void* const* d_in, const int* in_sizes, int n_in,
                              void* d_out, int out_size, void* d_ws, size_t ws_size,
                              hipStream_t stream) {
    const float* x      = (const float*)d_in[0];
    const float* logits = (const float*)d_in[1];
    const float* w1     = (const float*)d_in[2];
    const float* w2     = (const float*)d_in[3];
    float* out = (float*)d_out;
    char* ws = (char*)d_ws;

    // workspace layout
    const size_t OFF_CNT  = 0;
    const size_t OFF_BASE = 64;
    const size_t OFF_TOK  = 1024;
    const size_t OFF_WT   = OFF_TOK + (size_t)E_EXP * CAP * 4;
    const size_t OFF_XG   = 1u << 20;
    const size_t OFF_W1T  = OFF_XG + (size_t)T_TOKENS * H_DIM * 2;
    const size_t OFF_W2T  = OFF_W1T + (size_t)E_EXP * H_DIM * F_DIM * 2;
    const size_t OFF_G    = OFF_W2T + (size_t)E_EXP * H_DIM * F_DIM * 2;

    int* cnt  = (int*)(ws + OFF_CNT);
    int* base = (int*)(ws + OFF_BASE);
    int* tok  = (int*)(ws + OFF_TOK);
    float* wt = (float*)(ws + OFF_WT);
    unsigned short* xg  = (unsigned short*)(ws + OFF_XG);
    unsigned short* w1t = (unsigned short*)(ws + OFF_W1T);
    unsigned short* w2t = (unsigned short*)(ws + OFF_W2T);
    unsigned short* G   = (unsigned short*)(ws + OFF_G);

    hipMemsetAsync(d_out, 0, (size_t)out_size * sizeof(float), stream);
    hipMemsetAsync(cnt, 0, 64, stream);

    router_kernel<<<T_TOKENS / 256, 256, 0, stream>>>(logits, cnt, tok, wt);
    base_kernel<<<1, 64, 0, stream>>>(cnt, base);
    cvtx_kernel<<<(T_TOKENS * H_DIM / 4) / 256, 256, 0, stream>>>(x, xg);
    // w1 [E,H,F] -> w1t [E,F,H]
    tcvt_kernel<<<dim3(H_DIM / 64, F_DIM / 64, E_EXP), 256, 0, stream>>>(w1, w1t, H_DIM, F_DIM);
    // w2 [E,F,H] -> w2t [E,H,F]
    tcvt_kernel<<<dim3(F_DIM / 64, H_DIM / 64, E_EXP), 256, 0, stream>>>(w2, w2t, F_DIM, H_DIM);
    // GEMM1: MC=1, NT8=4  (8 XCD x 4 n-tiles = 32 n-tiles of F=4096)
    gemm_kernel<1, 0, 4, 1><<<8 * 4 * MT_TILES * E_EXP, 256, 0, stream>>>(
        xg, w1t, H_DIM, F_DIM, cnt, base, tok, wt, G, nullptr);
    // GEMM2: MC=4, NT8=4  (2 XCD-groups x 4 n-tiles = 8 n-tiles of H=1024;
    // the 4 n-tile blocks of each m-strip are consecutive on one XCD -> G-strip
    // fetched ~2x instead of ~4x: predicted FETCH 486 -> ~300 MB)
    gemm_kernel<0, 1, 4, 4><<<8 * 4 * (MT_TILES / 4) * E_EXP, 256, 0, stream>>>(
        G, w2t, F_DIM, H_DIM, cnt, base, tok, wt, nullptr, out);
    (void)in_sizes; (void)n_in; (void)ws_size;
}